// Round 5
// baseline (2078.747 us; speedup 1.0000x reference)
//
#include <hip/hip_runtime.h>
#include <hip/hip_bf16.h>
#include <stdint.h>

#define B_ 64
#define S_ 50
#define NSK 512
#define DK 128

// ws layout (float offsets)
#define LEARN_OFF 0u
#define PREL_OFF  409600u
#define PREG_OFF  819200u
#define PREF_OFF  1228800u
#define PREP_OFF  1638400u

typedef float  f32x4  __attribute__((ext_vector_type(4)));
typedef short  s16x8  __attribute__((ext_vector_type(8)));
typedef __bf16 bf16x8 __attribute__((ext_vector_type(8)));

static __device__ __forceinline__ bf16x8 as_bf(s16x8 v){ return __builtin_bit_cast(bf16x8, v); }

static __device__ __forceinline__ unsigned short f2bf(float x){
  unsigned int u = __builtin_bit_cast(unsigned int, x);
  u += 0x7FFFu + ((u>>16)&1u);
  return (unsigned short)(u>>16);
}
static __device__ __forceinline__ float sigm(float x){ return 1.f/(1.f + __expf(-x)); }

// -------------------- K1: learning[b,t,j] --------------------
__global__ __launch_bounds__(512) void k_learning(
    const float* __restrict__ E_emb, const float* __restrict__ AT_emb,
    const float* __restrict__ W_le, const float* __restrict__ b_le,
    const float* __restrict__ answer, const int* __restrict__ ex_id,
    const int* __restrict__ at_id, float* __restrict__ learn_ws)
{
  int b = blockIdx.x >> 2, jg = blockIdx.x & 3;
  int tid = threadIdx.x; int w = tid >> 6; int l = tid & 63;
  __shared__ float exv[S_][128];
  __shared__ float atv[S_][128];
  __shared__ float ansv[S_];
  for (int idx = tid; idx < S_*128; idx += 512) {
    int t = idx >> 7, d = idx & 127;
    exv[t][d] = E_emb[(size_t)ex_id[b*S_+t]*128 + d];
    atv[t][d] = AT_emb[(size_t)at_id[b*S_+t]*128 + d];
  }
  if (tid < S_) ansv[tid] = answer[b*S_+tid];
  __syncthreads();
  for (int jj = 0; jj < 4; ++jj) {
    int jrow = jg*32 + w + 8*jj;
    float wv[5];
    int base = l*5;
    #pragma unroll
    for (int q = 0; q < 5; ++q) { int i = base+q; wv[q] = (i < 306) ? W_le[jrow*306 + i] : 0.f; }
    float bj = b_le[jrow];
    for (int t = 0; t < S_; ++t) {
      float pacc = 0.f;
      #pragma unroll
      for (int q = 0; q < 5; ++q) {
        int i = base+q;
        float v = 0.f;
        if (i < 128) v = exv[t][i];
        else if (i < 256) v = atv[t][i-128];
        else if (i < 306) v = ansv[t];
        pacc += wv[q]*v;
      }
      #pragma unroll
      for (int m = 1; m < 64; m <<= 1) pacc += __shfl_xor(pacc, m, 64);
      if (l == 0) learn_ws[(size_t)(b*S_+t)*DK + jrow] = pacc + bj;
    }
  }
}

// -------------------- K2: pre_l/pre_g/pre_f/pre_p --------------------
__global__ __launch_bounds__(512) void k_pre(
    const float* __restrict__ IT_emb, const float* __restrict__ E_emb,
    const float* __restrict__ W_l, const float* __restrict__ b_l,
    const float* __restrict__ W_g, const float* __restrict__ b_g,
    const float* __restrict__ W_f, const float* __restrict__ b_f,
    const float* __restrict__ W_p, const float* __restrict__ b_p,
    const int* __restrict__ ex_id, const int* __restrict__ it_sec,
    const float* __restrict__ learn_ws, float* __restrict__ ws)
{
  int b = blockIdx.x >> 2, jg = blockIdx.x & 3;
  int tid = threadIdx.x; int w = tid >> 6; int l = tid & 63;
  __shared__ float itv[S_][128];
  __shared__ float llds[S_][128];
  __shared__ float exv[S_][128];
  for (int idx = tid; idx < S_*128; idx += 512) {
    int t = idx >> 7, d = idx & 127;
    int itm = it_sec[b*S_+t] / 60; if (itm > 1439) itm = 1439; if (itm < 0) itm = 0;
    itv[t][d]  = IT_emb[(size_t)itm*128 + d];
    llds[t][d] = learn_ws[(size_t)(b*S_+t)*DK + d];
    exv[t][d]  = E_emb[(size_t)ex_id[b*S_+t]*128 + d];
  }
  __syncthreads();
  for (int jj = 0; jj < 4; ++jj) {
    int jrow = jg*32 + w + 8*jj;
    float wl[6], wg[6];
    int base6 = l*6;
    #pragma unroll
    for (int q = 0; q < 6; ++q) { wl[q] = W_l[jrow*512 + base6+q]; wg[q] = W_g[jrow*512 + base6+q]; }
    float wfv[2], wpv[2];
    int base2 = l*2;
    #pragma unroll
    for (int q = 0; q < 2; ++q) { wfv[q] = W_f[jrow*384 + 256 + base2+q]; wpv[q] = W_p[jrow*256 + base2+q]; }
    float bl = b_l[jrow], bg = b_g[jrow], bfs = b_f[jrow], bp = b_p[jrow];
    for (int t = 0; t < S_; ++t) {
      float pl = 0.f, pg = 0.f, pf = 0.f, pp = 0.f;
      #pragma unroll
      for (int q = 0; q < 6; ++q) {
        int i = base6+q;
        float v;
        if (i < 128) v = (t > 0) ? llds[t-1][i] : 0.f;
        else if (i < 256) v = itv[t][i-128];
        else v = llds[t][i-256];
        pl += wl[q]*v; pg += wg[q]*v;
      }
      #pragma unroll
      for (int q = 0; q < 2; ++q) {
        pf += wfv[q]*itv[t][base2+q];
        pp += wpv[q]*exv[t][base2+q];
      }
      #pragma unroll
      for (int m = 1; m < 64; m <<= 1) {
        pl += __shfl_xor(pl, m, 64);
        pg += __shfl_xor(pg, m, 64);
        pf += __shfl_xor(pf, m, 64);
        pp += __shfl_xor(pp, m, 64);
      }
      if (l == 0) {
        size_t o = (size_t)(b*S_+t)*DK + jrow;
        ws[PREL_OFF + o] = pl + bl;
        ws[PREG_OFF + o] = pg + bg;
        ws[PREF_OFF + o] = pf + bfs;
        ws[PREP_OFF + o] = pp + bp;
      }
    }
  }
}

// -------------------- K3: sequential scan (4-way j split, low reg pressure) --------------------
__global__ __launch_bounds__(512, 2) void k_scan(
    const float* __restrict__ q_matrix, const float* __restrict__ h0,
    const float* __restrict__ W_l, const float* __restrict__ W_g,
    const float* __restrict__ W_f, const float* __restrict__ W_p,
    const int* __restrict__ ex_id, const float* __restrict__ ws,
    float* __restrict__ pred)
{
  int b = blockIdx.x;
  int tid = threadIdx.x;
  int w  = tid >> 6;          // wave 0..7
  int l  = tid & 63;          // lane
  int wj = w & 3;             // j-quarter: dims [wj*32, wj*32+32)
  int wn = w >> 2;            // skill half: rows [wn*256, wn*256+256)
  int lr  = l & 15;
  int lg4 = l >> 4;
  int swz = lr << 4;          // 4-bit row-XOR swizzle (srow&15 == lr)

  __shared__ __align__(16) unsigned short h_sh[NSK*DK];  // 128KB bf16, swizzled
  __shared__ float qbuf[2][NSK];
  __shared__ float LG_l[DK];
  __shared__ float cf_l[DK];
  __shared__ float htp_l[2][DK];
  __shared__ float ysum_l[8];

  // ---- W_f1 fragments (A operand): 2 jt x 4 k = 32 VGPRs ----
  s16x8 wfr[2][4];
  #pragma unroll
  for (int jt = 0; jt < 2; ++jt) {
    #pragma unroll
    for (int k = 0; k < 4; ++k) {
      int jrow_ = wj*32 + jt*16 + lr;
      int dbase = k*32 + lg4*8;
      const float* src = W_f + jrow_*384 + dbase;
      s16x8 f;
      #pragma unroll
      for (int q = 0; q < 8; ++q) f[q] = (short)f2bf(src[q]);
      wfr[jt][k] = f;
    }
  }

  // ---- h master in registers: thread owns 16 rows x 8 dims = 128 VGPRs ----
  f32x4 hreg[16][2];
  #pragma unroll
  for (int nt = 0; nt < 16; ++nt) {
    int srow = wn*256 + nt*16 + lr;
    #pragma unroll
    for (int jt = 0; jt < 2; ++jt) {
      int dbase = wj*32 + jt*16 + lg4*4;
      hreg[nt][jt] = *(const f32x4*)(h0 + (size_t)srow*DK + dbase);
    }
  }

  qbuf[0][tid] = q_matrix[(size_t)ex_id[b*S_]*NSK + tid];
  if (tid == 0) pred[b*S_] = 0.f;
  __syncthreads();
  // ---- h_tilde0 partials ----
  if (tid < 256) {
    int d = tid & 127, g = tid >> 7;
    float acc = 0.f;
    for (int n = g*256; n < g*256 + 256; ++n) acc += qbuf[0][n] * h0[(size_t)n*DK + d];
    htp_l[g][d] = acc;
  }
  __syncthreads();

  const float* pre_l = ws + PREL_OFF + (size_t)b*S_*DK;
  const float* pre_g = ws + PREG_OFF + (size_t)b*S_*DK;
  const float* pre_f = ws + PREF_OFF + (size_t)b*S_*DK;
  const float* pre_p = ws + PREP_OFF + (size_t)b*S_*DK;

  int jrow = tid >> 2, p = tid & 3;

  for (int tau = 0; tau < S_; ++tau) {
    // ================= G1: LG + y(tau) + q staging =================
    {
      float accL = 0.f, accG = 0.f, accY = 0.f;
      const float* wl4 = W_l + jrow*512 + 384;
      const float* wg4 = W_g + jrow*512 + 384;
      const float* wp2 = W_p + jrow*256 + 128;
      #pragma unroll
      for (int c0 = 0; c0 < 32; c0 += 4) {
        int c = p*32 + c0;
        f32x4 t0 = *(const f32x4*)&htp_l[0][c];
        f32x4 t1 = *(const f32x4*)&htp_l[1][c];
        f32x4 hv = t0 + t1;
        f32x4 a  = *(const f32x4*)(wl4 + c);
        f32x4 g4 = *(const f32x4*)(wg4 + c);
        f32x4 y4 = *(const f32x4*)(wp2 + c);
        accL += a[0]*hv[0] + a[1]*hv[1] + a[2]*hv[2] + a[3]*hv[3];
        accG += g4[0]*hv[0] + g4[1]*hv[1] + g4[2]*hv[2] + g4[3]*hv[3];
        accY += y4[0]*hv[0] + y4[1]*hv[1] + y4[2]*hv[2] + y4[3]*hv[3];
      }
      accL += __shfl_xor(accL, 1, 64); accL += __shfl_xor(accL, 2, 64);
      accG += __shfl_xor(accG, 1, 64); accG += __shfl_xor(accG, 2, 64);
      accY += __shfl_xor(accY, 1, 64); accY += __shfl_xor(accY, 2, 64);
      float xl = pre_l[tau*DK + jrow] + accL;
      float xg = pre_g[tau*DK + jrow] + accG;
      float LG = sigm(xg) * (tanhf(xl) + 1.f) * 0.5f;
      if (p == 0) LG_l[jrow] = LG;
      float sg = 0.f;
      if (tau > 0 && p == 0) sg = sigm(pre_p[tau*DK + jrow] + accY);
      #pragma unroll
      for (int m = 4; m < 64; m <<= 1) sg += __shfl_xor(sg, m, 64);
      if (l == 0) ysum_l[w] = sg;
      if (tau < S_-1) qbuf[(tau+1)&1][tid] = q_matrix[(size_t)ex_id[b*S_+tau+1]*NSK + tid];
    }
    __syncthreads(); // b1
    if (tid == 0 && tau > 0) {
      float s = 0.f;
      #pragma unroll
      for (int i = 0; i < 8; ++i) s += ysum_l[i];
      pred[b*S_ + tau] = s * (1.f/128.f);
    }

    if (tau < S_-1) {
      // ============ G2: cf = pre_f + W_f2 @ LG ; pack h_sh from hreg ============
      {
        float accF = 0.f;
        const float* wf2 = W_f + jrow*384 + 128;
        #pragma unroll
        for (int c0 = 0; c0 < 32; c0 += 4) {
          int c = p*32 + c0;
          f32x4 a   = *(const f32x4*)(wf2 + c);
          f32x4 lgv = *(const f32x4*)&LG_l[c];
          accF += a[0]*lgv[0] + a[1]*lgv[1] + a[2]*lgv[2] + a[3]*lgv[3];
        }
        accF += __shfl_xor(accF, 1, 64); accF += __shfl_xor(accF, 2, 64);
        if (p == 0) cf_l[jrow] = pre_f[tau*DK + jrow] + accF;
      }
      // pack bf16 shadow of h from registers (b64 writes, ~2-way banks)
      #pragma unroll
      for (int nt = 0; nt < 16; ++nt) {
        int srow = wn*256 + nt*16 + lr;
        #pragma unroll
        for (int jt = 0; jt < 2; ++jt) {
          int cb = (wj*32 + jt*16 + lg4*4)*2;
          f32x4 hv = hreg[nt][jt];
          unsigned long long pkv =
              (unsigned long long)f2bf(hv[0])
            | ((unsigned long long)f2bf(hv[1]) << 16)
            | ((unsigned long long)f2bf(hv[2]) << 32)
            | ((unsigned long long)f2bf(hv[3]) << 48);
          *(unsigned long long*)((char*)h_sh + (srow*256 + (cb ^ swz))) = pkv;
        }
      }
      __syncthreads(); // b2

      // ============ M: GEMM (acc init = cf) + update + h_tilde accum ============
      const float* qc = qbuf[tau&1];
      const float* qn = qbuf[(tau+1)&1];
      int db0 = wj*32 + lg4*4;
      f32x4 cf0 = *(const f32x4*)&cf_l[db0];
      f32x4 cf1 = *(const f32x4*)&cf_l[db0 + 16];
      f32x4 lg0 = *(const f32x4*)&LG_l[db0];
      f32x4 lg1 = *(const f32x4*)&LG_l[db0 + 16];
      f32x4 htp0 = (f32x4){0.f,0.f,0.f,0.f};
      f32x4 htp1 = (f32x4){0.f,0.f,0.f,0.f};

      #pragma unroll
      for (int nt = 0; nt < 16; ++nt) {
        int srow = wn*256 + nt*16 + lr;
        const char* rowp = (const char*)h_sh + srow*256;
        f32x4 acc0 = cf0, acc1 = cf1;
        #pragma unroll
        for (int k = 0; k < 4; ++k) {
          s16x8 bfr = *(const s16x8*)(rowp + ((k*64 + lg4*16) ^ swz));
          acc0 = __builtin_amdgcn_mfma_f32_16x16x32_bf16(as_bf(wfr[0][k]), as_bf(bfr), acc0, 0, 0, 0);
          acc1 = __builtin_amdgcn_mfma_f32_16x16x32_bf16(as_bf(wfr[1][k]), as_bf(bfr), acc1, 0, 0, 0);
        }
        float qt = qc[srow];
        float qv = qn[srow];
        #pragma unroll
        for (int r = 0; r < 4; ++r) {
          float x0 = qt*lg0[r] + sigm(acc0[r])*hreg[nt][0][r];
          float x1 = qt*lg1[r] + sigm(acc1[r])*hreg[nt][1][r];
          hreg[nt][0][r] = x0;
          hreg[nt][1][r] = x1;
          htp0[r] += qv*x0;
          htp1[r] += qv*x1;
        }
      }

      // reduce h_tilde partials over the 16 skill-lanes (lr)
      #pragma unroll
      for (int r = 0; r < 4; ++r) {
        float v0 = htp0[r], v1 = htp1[r];
        v0 += __shfl_xor(v0, 1, 64); v1 += __shfl_xor(v1, 1, 64);
        v0 += __shfl_xor(v0, 2, 64); v1 += __shfl_xor(v1, 2, 64);
        v0 += __shfl_xor(v0, 4, 64); v1 += __shfl_xor(v1, 4, 64);
        v0 += __shfl_xor(v0, 8, 64); v1 += __shfl_xor(v1, 8, 64);
        htp0[r] = v0; htp1[r] = v1;
      }
      if (lr == 0) {
        #pragma unroll
        for (int r = 0; r < 4; ++r) {
          htp_l[wn][db0 + r]      = htp0[r];
          htp_l[wn][db0 + 16 + r] = htp1[r];
        }
      }
      __syncthreads(); // b3
    }
  }
}

extern "C" void kernel_launch(void* const* d_in, const int* in_sizes, int n_in,
                              void* d_out, int out_size, void* d_ws, size_t ws_size,
                              hipStream_t stream) {
  const float* answer   = (const float*)d_in[0];
  const float* q_matrix = (const float*)d_in[1];
  const float* h0       = (const float*)d_in[2];
  const float* E_emb    = (const float*)d_in[3];
  const float* AT_emb   = (const float*)d_in[4];
  const float* IT_emb   = (const float*)d_in[5];
  const float* W_le     = (const float*)d_in[6];
  const float* b_le     = (const float*)d_in[7];
  const float* W_l      = (const float*)d_in[8];
  const float* b_l      = (const float*)d_in[9];
  const float* W_g      = (const float*)d_in[10];
  const float* b_g      = (const float*)d_in[11];
  const float* W_f      = (const float*)d_in[12];
  const float* b_f      = (const float*)d_in[13];
  const float* W_p      = (const float*)d_in[14];
  const float* b_p      = (const float*)d_in[15];
  const int* ex_id      = (const int*)d_in[16];
  const int* at_id      = (const int*)d_in[19];
  const int* it_sec     = (const int*)d_in[20];

  float* ws = (float*)d_ws;
  float* pred = (float*)d_out;

  k_learning<<<dim3(256), dim3(512), 0, stream>>>(E_emb, AT_emb, W_le, b_le, answer,
                                                  ex_id, at_id, ws + LEARN_OFF);
  k_pre<<<dim3(256), dim3(512), 0, stream>>>(IT_emb, E_emb, W_l, b_l, W_g, b_g,
                                             W_f, b_f, W_p, b_p, ex_id, it_sec,
                                             ws + LEARN_OFF, ws);
  k_scan<<<dim3(64), dim3(512), 0, stream>>>(q_matrix, h0, W_l, W_g, W_f, W_p,
                                             ex_id, ws, pred);
}

// Round 6
// 2076.176 us; speedup vs baseline: 1.0012x; 1.0012x over previous
//
#include <hip/hip_runtime.h>
#include <hip/hip_bf16.h>
#include <stdint.h>

#define B_ 64
#define S_ 50
#define NSK 512
#define DK 128

// ws layout (float offsets)
#define LEARN_OFF 0u
#define PREL_OFF  409600u
#define PREG_OFF  819200u
#define PREF_OFF  1228800u
#define PREP_OFF  1638400u

typedef float  f32x4  __attribute__((ext_vector_type(4)));
typedef short  s16x8  __attribute__((ext_vector_type(8)));
typedef __bf16 bf16x8 __attribute__((ext_vector_type(8)));

static __device__ __forceinline__ bf16x8 as_bf(s16x8 v){ return __builtin_bit_cast(bf16x8, v); }

static __device__ __forceinline__ unsigned short f2bf(float x){
  unsigned int u = __builtin_bit_cast(unsigned int, x);
  u += 0x7FFFu + ((u>>16)&1u);
  return (unsigned short)(u>>16);
}
static __device__ __forceinline__ float sigm(float x){ return 1.f/(1.f + __expf(-x)); }

// -------------------- K1: learning[b,t,j] --------------------
__global__ __launch_bounds__(512) void k_learning(
    const float* __restrict__ E_emb, const float* __restrict__ AT_emb,
    const float* __restrict__ W_le, const float* __restrict__ b_le,
    const float* __restrict__ answer, const int* __restrict__ ex_id,
    const int* __restrict__ at_id, float* __restrict__ learn_ws)
{
  int b = blockIdx.x >> 2, jg = blockIdx.x & 3;
  int tid = threadIdx.x; int w = tid >> 6; int l = tid & 63;
  __shared__ float exv[S_][128];
  __shared__ float atv[S_][128];
  __shared__ float ansv[S_];
  for (int idx = tid; idx < S_*128; idx += 512) {
    int t = idx >> 7, d = idx & 127;
    exv[t][d] = E_emb[(size_t)ex_id[b*S_+t]*128 + d];
    atv[t][d] = AT_emb[(size_t)at_id[b*S_+t]*128 + d];
  }
  if (tid < S_) ansv[tid] = answer[b*S_+tid];
  __syncthreads();
  for (int jj = 0; jj < 4; ++jj) {
    int jrow = jg*32 + w + 8*jj;
    float wv[5];
    int base = l*5;
    #pragma unroll
    for (int q = 0; q < 5; ++q) { int i = base+q; wv[q] = (i < 306) ? W_le[jrow*306 + i] : 0.f; }
    float bj = b_le[jrow];
    for (int t = 0; t < S_; ++t) {
      float pacc = 0.f;
      #pragma unroll
      for (int q = 0; q < 5; ++q) {
        int i = base+q;
        float v = 0.f;
        if (i < 128) v = exv[t][i];
        else if (i < 256) v = atv[t][i-128];
        else if (i < 306) v = ansv[t];
        pacc += wv[q]*v;
      }
      #pragma unroll
      for (int m = 1; m < 64; m <<= 1) pacc += __shfl_xor(pacc, m, 64);
      if (l == 0) learn_ws[(size_t)(b*S_+t)*DK + jrow] = pacc + bj;
    }
  }
}

// -------------------- K2: pre_l/pre_g/pre_f/pre_p --------------------
__global__ __launch_bounds__(512) void k_pre(
    const float* __restrict__ IT_emb, const float* __restrict__ E_emb,
    const float* __restrict__ W_l, const float* __restrict__ b_l,
    const float* __restrict__ W_g, const float* __restrict__ b_g,
    const float* __restrict__ W_f, const float* __restrict__ b_f,
    const float* __restrict__ W_p, const float* __restrict__ b_p,
    const int* __restrict__ ex_id, const int* __restrict__ it_sec,
    const float* __restrict__ learn_ws, float* __restrict__ ws)
{
  int b = blockIdx.x >> 2, jg = blockIdx.x & 3;
  int tid = threadIdx.x; int w = tid >> 6; int l = tid & 63;
  __shared__ float itv[S_][128];
  __shared__ float llds[S_][128];
  __shared__ float exv[S_][128];
  for (int idx = tid; idx < S_*128; idx += 512) {
    int t = idx >> 7, d = idx & 127;
    int itm = it_sec[b*S_+t] / 60; if (itm > 1439) itm = 1439; if (itm < 0) itm = 0;
    itv[t][d]  = IT_emb[(size_t)itm*128 + d];
    llds[t][d] = learn_ws[(size_t)(b*S_+t)*DK + d];
    exv[t][d]  = E_emb[(size_t)ex_id[b*S_+t]*128 + d];
  }
  __syncthreads();
  for (int jj = 0; jj < 4; ++jj) {
    int jrow = jg*32 + w + 8*jj;
    float wl[6], wg[6];
    int base6 = l*6;
    #pragma unroll
    for (int q = 0; q < 6; ++q) { wl[q] = W_l[jrow*512 + base6+q]; wg[q] = W_g[jrow*512 + base6+q]; }
    float wfv[2], wpv[2];
    int base2 = l*2;
    #pragma unroll
    for (int q = 0; q < 2; ++q) { wfv[q] = W_f[jrow*384 + 256 + base2+q]; wpv[q] = W_p[jrow*256 + base2+q]; }
    float bl = b_l[jrow], bg = b_g[jrow], bfs = b_f[jrow], bp = b_p[jrow];
    for (int t = 0; t < S_; ++t) {
      float pl = 0.f, pg = 0.f, pf = 0.f, pp = 0.f;
      #pragma unroll
      for (int q = 0; q < 6; ++q) {
        int i = base6+q;
        float v;
        if (i < 128) v = (t > 0) ? llds[t-1][i] : 0.f;
        else if (i < 256) v = itv[t][i-128];
        else v = llds[t][i-256];
        pl += wl[q]*v; pg += wg[q]*v;
      }
      #pragma unroll
      for (int q = 0; q < 2; ++q) {
        pf += wfv[q]*itv[t][base2+q];
        pp += wpv[q]*exv[t][base2+q];
      }
      #pragma unroll
      for (int m = 1; m < 64; m <<= 1) {
        pl += __shfl_xor(pl, m, 64);
        pg += __shfl_xor(pg, m, 64);
        pf += __shfl_xor(pf, m, 64);
        pp += __shfl_xor(pp, m, 64);
      }
      if (l == 0) {
        size_t o = (size_t)(b*S_+t)*DK + jrow;
        ws[PREL_OFF + o] = pl + bl;
        ws[PREG_OFF + o] = pg + bg;
        ws[PREF_OFF + o] = pf + bfs;
        ws[PREP_OFF + o] = pp + bp;
      }
    }
  }
}

// -------------------- K3: sequential scan (h in VGPRs; 2 waves/EU => 256-reg budget) --------------------
__global__ __launch_bounds__(512)
__attribute__((amdgpu_waves_per_eu(2, 2)))
void k_scan(
    const float* __restrict__ q_matrix, const float* __restrict__ h0,
    const float* __restrict__ W_l, const float* __restrict__ W_g,
    const float* __restrict__ W_f, const float* __restrict__ W_p,
    const int* __restrict__ ex_id, const float* __restrict__ ws,
    float* __restrict__ pred)
{
  int b = blockIdx.x;
  int tid = threadIdx.x;
  int w  = tid >> 6;          // wave 0..7
  int l  = tid & 63;          // lane
  int wj = w & 3;             // j-quarter: dims [wj*32, wj*32+32)
  int wn = w >> 2;            // skill half: rows [wn*256, wn*256+256)
  int lr  = l & 15;
  int lg4 = l >> 4;
  int swz = lr << 4;          // 4-bit row-XOR swizzle (srow&15 == lr)

  __shared__ __align__(16) unsigned short h_sh[NSK*DK];  // 128KB bf16, swizzled
  __shared__ float qbuf[2][NSK];
  __shared__ float LG_l[DK];
  __shared__ float cf_l[DK];
  __shared__ float htp_l[2][DK];
  __shared__ float ysum_l[8];

  // ---- W_f1 fragments (A operand): 2 jt x 4 k = 32 VGPRs ----
  s16x8 wfr[2][4];
  #pragma unroll
  for (int jt = 0; jt < 2; ++jt) {
    #pragma unroll
    for (int k = 0; k < 4; ++k) {
      int jrow_ = wj*32 + jt*16 + lr;
      int dbase = k*32 + lg4*8;
      const float* src = W_f + jrow_*384 + dbase;
      s16x8 f;
      #pragma unroll
      for (int q = 0; q < 8; ++q) f[q] = (short)f2bf(src[q]);
      wfr[jt][k] = f;
    }
  }

  // ---- h master in registers: thread owns 16 rows x 8 dims = 128 VGPRs ----
  f32x4 hreg[16][2];
  #pragma unroll
  for (int nt = 0; nt < 16; ++nt) {
    int srow = wn*256 + nt*16 + lr;
    #pragma unroll
    for (int jt = 0; jt < 2; ++jt) {
      int dbase = wj*32 + jt*16 + lg4*4;
      hreg[nt][jt] = *(const f32x4*)(h0 + (size_t)srow*DK + dbase);
    }
  }

  qbuf[0][tid] = q_matrix[(size_t)ex_id[b*S_]*NSK + tid];
  if (tid == 0) pred[b*S_] = 0.f;
  __syncthreads();
  // ---- h_tilde0 partials ----
  if (tid < 256) {
    int d = tid & 127, g = tid >> 7;
    float acc = 0.f;
    for (int n = g*256; n < g*256 + 256; ++n) acc += qbuf[0][n] * h0[(size_t)n*DK + d];
    htp_l[g][d] = acc;
  }
  __syncthreads();

  const float* pre_l = ws + PREL_OFF + (size_t)b*S_*DK;
  const float* pre_g = ws + PREG_OFF + (size_t)b*S_*DK;
  const float* pre_f = ws + PREF_OFF + (size_t)b*S_*DK;
  const float* pre_p = ws + PREP_OFF + (size_t)b*S_*DK;

  int jrow = tid >> 2, p = tid & 3;

  for (int tau = 0; tau < S_; ++tau) {
    // ================= G1: LG + y(tau) + q staging =================
    {
      float accL = 0.f, accG = 0.f, accY = 0.f;
      const float* wl4 = W_l + jrow*512 + 384;
      const float* wg4 = W_g + jrow*512 + 384;
      const float* wp2 = W_p + jrow*256 + 128;
      #pragma unroll
      for (int c0 = 0; c0 < 32; c0 += 4) {
        int c = p*32 + c0;
        f32x4 t0 = *(const f32x4*)&htp_l[0][c];
        f32x4 t1 = *(const f32x4*)&htp_l[1][c];
        f32x4 hv = t0 + t1;
        f32x4 a  = *(const f32x4*)(wl4 + c);
        f32x4 g4 = *(const f32x4*)(wg4 + c);
        f32x4 y4 = *(const f32x4*)(wp2 + c);
        accL += a[0]*hv[0] + a[1]*hv[1] + a[2]*hv[2] + a[3]*hv[3];
        accG += g4[0]*hv[0] + g4[1]*hv[1] + g4[2]*hv[2] + g4[3]*hv[3];
        accY += y4[0]*hv[0] + y4[1]*hv[1] + y4[2]*hv[2] + y4[3]*hv[3];
      }
      accL += __shfl_xor(accL, 1, 64); accL += __shfl_xor(accL, 2, 64);
      accG += __shfl_xor(accG, 1, 64); accG += __shfl_xor(accG, 2, 64);
      accY += __shfl_xor(accY, 1, 64); accY += __shfl_xor(accY, 2, 64);
      float xl = pre_l[tau*DK + jrow] + accL;
      float xg = pre_g[tau*DK + jrow] + accG;
      float LG = sigm(xg) * (tanhf(xl) + 1.f) * 0.5f;
      if (p == 0) LG_l[jrow] = LG;
      float sg = 0.f;
      if (tau > 0 && p == 0) sg = sigm(pre_p[tau*DK + jrow] + accY);
      #pragma unroll
      for (int m = 4; m < 64; m <<= 1) sg += __shfl_xor(sg, m, 64);
      if (l == 0) ysum_l[w] = sg;
      if (tau < S_-1) qbuf[(tau+1)&1][tid] = q_matrix[(size_t)ex_id[b*S_+tau+1]*NSK + tid];
    }
    __syncthreads(); // b1
    if (tid == 0 && tau > 0) {
      float s = 0.f;
      #pragma unroll
      for (int i = 0; i < 8; ++i) s += ysum_l[i];
      pred[b*S_ + tau] = s * (1.f/128.f);
    }

    if (tau < S_-1) {
      // ============ G2: cf = pre_f + W_f2 @ LG ; pack h_sh from hreg ============
      {
        float accF = 0.f;
        const float* wf2 = W_f + jrow*384 + 128;
        #pragma unroll
        for (int c0 = 0; c0 < 32; c0 += 4) {
          int c = p*32 + c0;
          f32x4 a   = *(const f32x4*)(wf2 + c);
          f32x4 lgv = *(const f32x4*)&LG_l[c];
          accF += a[0]*lgv[0] + a[1]*lgv[1] + a[2]*lgv[2] + a[3]*lgv[3];
        }
        accF += __shfl_xor(accF, 1, 64); accF += __shfl_xor(accF, 2, 64);
        if (p == 0) cf_l[jrow] = pre_f[tau*DK + jrow] + accF;
      }
      // pack bf16 shadow of h from registers (b64 writes, ~2-way banks)
      #pragma unroll
      for (int nt = 0; nt < 16; ++nt) {
        int srow = wn*256 + nt*16 + lr;
        #pragma unroll
        for (int jt = 0; jt < 2; ++jt) {
          int cb = (wj*32 + jt*16 + lg4*4)*2;
          f32x4 hv = hreg[nt][jt];
          unsigned long long pkv =
              (unsigned long long)f2bf(hv[0])
            | ((unsigned long long)f2bf(hv[1]) << 16)
            | ((unsigned long long)f2bf(hv[2]) << 32)
            | ((unsigned long long)f2bf(hv[3]) << 48);
          *(unsigned long long*)((char*)h_sh + (srow*256 + (cb ^ swz))) = pkv;
        }
      }
      __syncthreads(); // b2

      // ============ M: GEMM (acc init = cf) + update + h_tilde accum ============
      const float* qc = qbuf[tau&1];
      const float* qn = qbuf[(tau+1)&1];
      int db0 = wj*32 + lg4*4;
      f32x4 cf0 = *(const f32x4*)&cf_l[db0];
      f32x4 cf1 = *(const f32x4*)&cf_l[db0 + 16];
      f32x4 lg0 = *(const f32x4*)&LG_l[db0];
      f32x4 lg1 = *(const f32x4*)&LG_l[db0 + 16];
      f32x4 htp0 = (f32x4){0.f,0.f,0.f,0.f};
      f32x4 htp1 = (f32x4){0.f,0.f,0.f,0.f};

      #pragma unroll
      for (int nt = 0; nt < 16; ++nt) {
        int srow = wn*256 + nt*16 + lr;
        const char* rowp = (const char*)h_sh + srow*256;
        f32x4 acc0 = cf0, acc1 = cf1;
        #pragma unroll
        for (int k = 0; k < 4; ++k) {
          s16x8 bfr = *(const s16x8*)(rowp + ((k*64 + lg4*16) ^ swz));
          acc0 = __builtin_amdgcn_mfma_f32_16x16x32_bf16(as_bf(wfr[0][k]), as_bf(bfr), acc0, 0, 0, 0);
          acc1 = __builtin_amdgcn_mfma_f32_16x16x32_bf16(as_bf(wfr[1][k]), as_bf(bfr), acc1, 0, 0, 0);
        }
        float qt = qc[srow];
        float qv = qn[srow];
        #pragma unroll
        for (int r = 0; r < 4; ++r) {
          float x0 = qt*lg0[r] + sigm(acc0[r])*hreg[nt][0][r];
          float x1 = qt*lg1[r] + sigm(acc1[r])*hreg[nt][1][r];
          hreg[nt][0][r] = x0;
          hreg[nt][1][r] = x1;
          htp0[r] += qv*x0;
          htp1[r] += qv*x1;
        }
      }

      // reduce h_tilde partials over the 16 skill-lanes (lr)
      #pragma unroll
      for (int r = 0; r < 4; ++r) {
        float v0 = htp0[r], v1 = htp1[r];
        v0 += __shfl_xor(v0, 1, 64); v1 += __shfl_xor(v1, 1, 64);
        v0 += __shfl_xor(v0, 2, 64); v1 += __shfl_xor(v1, 2, 64);
        v0 += __shfl_xor(v0, 4, 64); v1 += __shfl_xor(v1, 4, 64);
        v0 += __shfl_xor(v0, 8, 64); v1 += __shfl_xor(v1, 8, 64);
        htp0[r] = v0; htp1[r] = v1;
      }
      if (lr == 0) {
        #pragma unroll
        for (int r = 0; r < 4; ++r) {
          htp_l[wn][db0 + r]      = htp0[r];
          htp_l[wn][db0 + 16 + r] = htp1[r];
        }
      }
      __syncthreads(); // b3
    }
  }
}

extern "C" void kernel_launch(void* const* d_in, const int* in_sizes, int n_in,
                              void* d_out, int out_size, void* d_ws, size_t ws_size,
                              hipStream_t stream) {
  const float* answer   = (const float*)d_in[0];
  const float* q_matrix = (const float*)d_in[1];
  const float* h0       = (const float*)d_in[2];
  const float* E_emb    = (const float*)d_in[3];
  const float* AT_emb   = (const float*)d_in[4];
  const float* IT_emb   = (const float*)d_in[5];
  const float* W_le     = (const float*)d_in[6];
  const float* b_le     = (const float*)d_in[7];
  const float* W_l      = (const float*)d_in[8];
  const float* b_l      = (const float*)d_in[9];
  const float* W_g      = (const float*)d_in[10];
  const float* b_g      = (const float*)d_in[11];
  const float* W_f      = (const float*)d_in[12];
  const float* b_f      = (const float*)d_in[13];
  const float* W_p      = (const float*)d_in[14];
  const float* b_p      = (const float*)d_in[15];
  const int* ex_id      = (const int*)d_in[16];
  const int* at_id      = (const int*)d_in[19];
  const int* it_sec     = (const int*)d_in[20];

  float* ws = (float*)d_ws;
  float* pred = (float*)d_out;

  k_learning<<<dim3(256), dim3(512), 0, stream>>>(E_emb, AT_emb, W_le, b_le, answer,
                                                  ex_id, at_id, ws + LEARN_OFF);
  k_pre<<<dim3(256), dim3(512), 0, stream>>>(IT_emb, E_emb, W_l, b_l, W_g, b_g,
                                             W_f, b_f, W_p, b_p, ex_id, it_sec,
                                             ws + LEARN_OFF, ws);
  k_scan<<<dim3(64), dim3(512), 0, stream>>>(q_matrix, h0, W_l, W_g, W_f, W_p,
                                             ex_id, ws, pred);
}

// Round 7
// 2045.242 us; speedup vs baseline: 1.0164x; 1.0151x over previous
//
#include <hip/hip_runtime.h>
#include <hip/hip_bf16.h>
#include <stdint.h>

#define B_ 64
#define S_ 50
#define NSK 512
#define DK 128

// ws layout (float offsets)
#define LEARN_OFF 0u
#define PREL_OFF  409600u
#define PREG_OFF  819200u
#define PREF_OFF  1228800u
#define PREP_OFF  1638400u

typedef float  f32x4  __attribute__((ext_vector_type(4)));
typedef short  s16x8  __attribute__((ext_vector_type(8)));
typedef __bf16 bf16x8 __attribute__((ext_vector_type(8)));

static __device__ __forceinline__ bf16x8 as_bf(s16x8 v){ return __builtin_bit_cast(bf16x8, v); }

static __device__ __forceinline__ unsigned short f2bf(float x){
  unsigned int u = __builtin_bit_cast(unsigned int, x);
  u += 0x7FFFu + ((u>>16)&1u);
  return (unsigned short)(u>>16);
}
static __device__ __forceinline__ float sigm(float x){ return 1.f/(1.f + __expf(-x)); }

// -------------------- K1: learning[b,t,j] --------------------
__global__ __launch_bounds__(512) void k_learning(
    const float* __restrict__ E_emb, const float* __restrict__ AT_emb,
    const float* __restrict__ W_le, const float* __restrict__ b_le,
    const float* __restrict__ answer, const int* __restrict__ ex_id,
    const int* __restrict__ at_id, float* __restrict__ learn_ws)
{
  int b = blockIdx.x >> 2, jg = blockIdx.x & 3;
  int tid = threadIdx.x; int w = tid >> 6; int l = tid & 63;
  __shared__ float exv[S_][128];
  __shared__ float atv[S_][128];
  __shared__ float ansv[S_];
  for (int idx = tid; idx < S_*128; idx += 512) {
    int t = idx >> 7, d = idx & 127;
    exv[t][d] = E_emb[(size_t)ex_id[b*S_+t]*128 + d];
    atv[t][d] = AT_emb[(size_t)at_id[b*S_+t]*128 + d];
  }
  if (tid < S_) ansv[tid] = answer[b*S_+tid];
  __syncthreads();
  for (int jj = 0; jj < 4; ++jj) {
    int jrow = jg*32 + w + 8*jj;
    float wv[5];
    int base = l*5;
    #pragma unroll
    for (int q = 0; q < 5; ++q) { int i = base+q; wv[q] = (i < 306) ? W_le[jrow*306 + i] : 0.f; }
    float bj = b_le[jrow];
    for (int t = 0; t < S_; ++t) {
      float pacc = 0.f;
      #pragma unroll
      for (int q = 0; q < 5; ++q) {
        int i = base+q;
        float v = 0.f;
        if (i < 128) v = exv[t][i];
        else if (i < 256) v = atv[t][i-128];
        else if (i < 306) v = ansv[t];
        pacc += wv[q]*v;
      }
      #pragma unroll
      for (int m = 1; m < 64; m <<= 1) pacc += __shfl_xor(pacc, m, 64);
      if (l == 0) learn_ws[(size_t)(b*S_+t)*DK + jrow] = pacc + bj;
    }
  }
}

// -------------------- K2: pre_l/pre_g/pre_f/pre_p --------------------
__global__ __launch_bounds__(512) void k_pre(
    const float* __restrict__ IT_emb, const float* __restrict__ E_emb,
    const float* __restrict__ W_l, const float* __restrict__ b_l,
    const float* __restrict__ W_g, const float* __restrict__ b_g,
    const float* __restrict__ W_f, const float* __restrict__ b_f,
    const float* __restrict__ W_p, const float* __restrict__ b_p,
    const int* __restrict__ ex_id, const int* __restrict__ it_sec,
    const float* __restrict__ learn_ws, float* __restrict__ ws)
{
  int b = blockIdx.x >> 2, jg = blockIdx.x & 3;
  int tid = threadIdx.x; int w = tid >> 6; int l = tid & 63;
  __shared__ float itv[S_][128];
  __shared__ float llds[S_][128];
  __shared__ float exv[S_][128];
  for (int idx = tid; idx < S_*128; idx += 512) {
    int t = idx >> 7, d = idx & 127;
    int itm = it_sec[b*S_+t] / 60; if (itm > 1439) itm = 1439; if (itm < 0) itm = 0;
    itv[t][d]  = IT_emb[(size_t)itm*128 + d];
    llds[t][d] = learn_ws[(size_t)(b*S_+t)*DK + d];
    exv[t][d]  = E_emb[(size_t)ex_id[b*S_+t]*128 + d];
  }
  __syncthreads();
  for (int jj = 0; jj < 4; ++jj) {
    int jrow = jg*32 + w + 8*jj;
    float wl[6], wg[6];
    int base6 = l*6;
    #pragma unroll
    for (int q = 0; q < 6; ++q) { wl[q] = W_l[jrow*512 + base6+q]; wg[q] = W_g[jrow*512 + base6+q]; }
    float wfv[2], wpv[2];
    int base2 = l*2;
    #pragma unroll
    for (int q = 0; q < 2; ++q) { wfv[q] = W_f[jrow*384 + 256 + base2+q]; wpv[q] = W_p[jrow*256 + base2+q]; }
    float bl = b_l[jrow], bg = b_g[jrow], bfs = b_f[jrow], bp = b_p[jrow];
    for (int t = 0; t < S_; ++t) {
      float pl = 0.f, pg = 0.f, pf = 0.f, pp = 0.f;
      #pragma unroll
      for (int q = 0; q < 6; ++q) {
        int i = base6+q;
        float v;
        if (i < 128) v = (t > 0) ? llds[t-1][i] : 0.f;
        else if (i < 256) v = itv[t][i-128];
        else v = llds[t][i-256];
        pl += wl[q]*v; pg += wg[q]*v;
      }
      #pragma unroll
      for (int q = 0; q < 2; ++q) {
        pf += wfv[q]*itv[t][base2+q];
        pp += wpv[q]*exv[t][base2+q];
      }
      #pragma unroll
      for (int m = 1; m < 64; m <<= 1) {
        pl += __shfl_xor(pl, m, 64);
        pg += __shfl_xor(pg, m, 64);
        pf += __shfl_xor(pf, m, 64);
        pp += __shfl_xor(pp, m, 64);
      }
      if (l == 0) {
        size_t o = (size_t)(b*S_+t)*DK + jrow;
        ws[PREL_OFF + o] = pl + bl;
        ws[PREG_OFF + o] = pg + bg;
        ws[PREF_OFF + o] = pf + bfs;
        ws[PREP_OFF + o] = pp + bp;
      }
    }
  }
}

// -------------------- K3: scan, 1024 threads, <=128 VGPR by construction --------------------
// wave w: wn = w>>3 (skill half, 256 rows), wj = w&7 (16 j-dims).
// thread: hreg[16] f32x4 = h[wn*256+g*16+lr][wj*16+lg4*4 .. +4]  (64 VGPRs)
//         wfr[4] A-frags for the single 16x16 j-tile               (16 VGPRs)
__global__ __launch_bounds__(1024) void k_scan(
    const float* __restrict__ q_matrix, const float* __restrict__ h0,
    const float* __restrict__ W_l, const float* __restrict__ W_g,
    const float* __restrict__ W_f, const float* __restrict__ W_p,
    const int* __restrict__ ex_id, const float* __restrict__ ws,
    float* __restrict__ pred)
{
  int b = blockIdx.x;
  int tid = threadIdx.x;
  int w  = tid >> 6;          // wave 0..15
  int l  = tid & 63;          // lane
  int wn = w >> 3;            // skill half: rows [wn*256, wn*256+256)
  int wj = w & 7;             // j-sixteenth-pair: dims [wj*16, wj*16+16)
  int lr  = l & 15;
  int lg4 = l >> 4;
  int jb  = wj*16;
  int swz = (lr & 7) << 4;    // row-XOR swizzle ((row&7) == (lr&7))

  __shared__ __align__(16) unsigned short h_sh[NSK*DK];  // 128KB bf16, swizzled
  __shared__ float qbuf[2][NSK];
  __shared__ float LG_l[DK];
  __shared__ float cf_l[DK];
  __shared__ float htp_l[2][DK];
  __shared__ float ysum_l[16];

  // ---- W_f1 fragments for this wave's one j-tile: 4 k-frags = 16 VGPRs ----
  s16x8 wfr[4];
  #pragma unroll
  for (int k = 0; k < 4; ++k) {
    const float* src = W_f + (jb + lr)*384 + k*32 + lg4*8;
    s16x8 f;
    #pragma unroll
    for (int q = 0; q < 8; ++q) f[q] = (short)f2bf(src[q]);
    wfr[k] = f;
  }

  // ---- h master in registers: 16 rows x 4 dims = 64 VGPRs ----
  f32x4 hreg[16];
  #pragma unroll
  for (int g = 0; g < 16; ++g) {
    int row = wn*256 + g*16 + lr;
    hreg[g] = *(const f32x4*)(h0 + (size_t)row*DK + jb + lg4*4);
  }

  if (tid < NSK) qbuf[0][tid] = q_matrix[(size_t)ex_id[b*S_]*NSK + tid];
  if (tid == 0) pred[b*S_] = 0.f;
  __syncthreads();
  // ---- h_tilde0 partials ----
  if (tid < 256) {
    int d = tid & 127, g2 = tid >> 7;
    float acc = 0.f;
    for (int n = g2*256; n < g2*256 + 256; ++n) acc += qbuf[0][n] * h0[(size_t)n*DK + d];
    htp_l[g2][d] = acc;
  }
  __syncthreads();

  const float* pre_l = ws + PREL_OFF + (size_t)b*S_*DK;
  const float* pre_g = ws + PREG_OFF + (size_t)b*S_*DK;
  const float* pre_f = ws + PREF_OFF + (size_t)b*S_*DK;
  const float* pre_p = ws + PREP_OFF + (size_t)b*S_*DK;

  int jrow = tid >> 3, p = tid & 7;   // 128 rows x 8 lanes (16 cols each)

  for (int tau = 0; tau < S_; ++tau) {
    // ================= G1: LG + y(tau) + q staging =================
    {
      float accL = 0.f, accG = 0.f, accY = 0.f;
      const float* wl4 = W_l + jrow*512 + 384;
      const float* wg4 = W_g + jrow*512 + 384;
      const float* wp2 = W_p + jrow*256 + 128;
      #pragma unroll
      for (int c0 = 0; c0 < 16; c0 += 4) {
        int c = p*16 + c0;
        f32x4 t0 = *(const f32x4*)&htp_l[0][c];
        f32x4 t1 = *(const f32x4*)&htp_l[1][c];
        f32x4 hv = t0 + t1;
        f32x4 a  = *(const f32x4*)(wl4 + c);
        f32x4 g4 = *(const f32x4*)(wg4 + c);
        f32x4 y4 = *(const f32x4*)(wp2 + c);
        accL += a[0]*hv[0] + a[1]*hv[1] + a[2]*hv[2] + a[3]*hv[3];
        accG += g4[0]*hv[0] + g4[1]*hv[1] + g4[2]*hv[2] + g4[3]*hv[3];
        accY += y4[0]*hv[0] + y4[1]*hv[1] + y4[2]*hv[2] + y4[3]*hv[3];
      }
      accL += __shfl_xor(accL, 1, 64); accL += __shfl_xor(accL, 2, 64); accL += __shfl_xor(accL, 4, 64);
      accG += __shfl_xor(accG, 1, 64); accG += __shfl_xor(accG, 2, 64); accG += __shfl_xor(accG, 4, 64);
      accY += __shfl_xor(accY, 1, 64); accY += __shfl_xor(accY, 2, 64); accY += __shfl_xor(accY, 4, 64);
      float xl = pre_l[tau*DK + jrow] + accL;
      float xg = pre_g[tau*DK + jrow] + accG;
      float LG = sigm(xg) * (tanhf(xl) + 1.f) * 0.5f;
      if (p == 0) LG_l[jrow] = LG;
      float sg = 0.f;
      if (tau > 0 && p == 0) sg = sigm(pre_p[tau*DK + jrow] + accY);
      sg += __shfl_xor(sg, 8, 64); sg += __shfl_xor(sg, 16, 64); sg += __shfl_xor(sg, 32, 64);
      if (l == 0) ysum_l[w] = sg;
      if (tau < S_-1 && tid < NSK) qbuf[(tau+1)&1][tid] = q_matrix[(size_t)ex_id[b*S_+tau+1]*NSK + tid];
    }
    __syncthreads(); // b1
    if (tid == 0 && tau > 0) {
      float s = 0.f;
      #pragma unroll
      for (int i = 0; i < 16; ++i) s += ysum_l[i];
      pred[b*S_ + tau] = s * (1.f/128.f);
    }

    if (tau < S_-1) {
      // ============ G2: cf = pre_f + W_f2 @ LG ; pack h_sh from hreg ============
      {
        float accF = 0.f;
        const float* wf2 = W_f + jrow*384 + 128;
        #pragma unroll
        for (int c0 = 0; c0 < 16; c0 += 4) {
          int c = p*16 + c0;
          f32x4 a   = *(const f32x4*)(wf2 + c);
          f32x4 lgv = *(const f32x4*)&LG_l[c];
          accF += a[0]*lgv[0] + a[1]*lgv[1] + a[2]*lgv[2] + a[3]*lgv[3];
        }
        accF += __shfl_xor(accF, 1, 64); accF += __shfl_xor(accF, 2, 64); accF += __shfl_xor(accF, 4, 64);
        if (p == 0) cf_l[jrow] = pre_f[tau*DK + jrow] + accF;
      }
      // pack bf16 shadow of h from registers (b64 writes)
      #pragma unroll
      for (int g = 0; g < 16; ++g) {
        int row = wn*256 + g*16 + lr;
        int cb = jb*2 + lg4*8;
        f32x4 hv = hreg[g];
        unsigned long long pkv =
            (unsigned long long)f2bf(hv[0])
          | ((unsigned long long)f2bf(hv[1]) << 16)
          | ((unsigned long long)f2bf(hv[2]) << 32)
          | ((unsigned long long)f2bf(hv[3]) << 48);
        *(unsigned long long*)((char*)h_sh + (row*256 + (cb ^ swz))) = pkv;
      }
      __syncthreads(); // b2

      // ============ M: MFMA (acc init = cf) + update + h_tilde accum ============
      const float* qc = qbuf[tau&1];
      const float* qn = qbuf[(tau+1)&1];
      f32x4 cfv = *(const f32x4*)&cf_l[jb + lg4*4];
      f32x4 lgv = *(const f32x4*)&LG_l[jb + lg4*4];
      f32x4 htp = (f32x4){0.f,0.f,0.f,0.f};

      #pragma unroll
      for (int g = 0; g < 16; ++g) {
        int row = wn*256 + g*16 + lr;
        const char* rowp = (const char*)h_sh + row*256;
        f32x4 acc = cfv;
        #pragma unroll
        for (int k = 0; k < 4; ++k) {
          s16x8 bfr = *(const s16x8*)(rowp + ((k*64 + lg4*16) ^ swz));
          acc = __builtin_amdgcn_mfma_f32_16x16x32_bf16(as_bf(wfr[k]), as_bf(bfr), acc, 0, 0, 0);
        }
        float qt = qc[row];
        float qv = qn[row];
        f32x4 hv = hreg[g];
        f32x4 hn;
        #pragma unroll
        for (int r = 0; r < 4; ++r) {
          float x = qt*lgv[r] + sigm(acc[r])*hv[r];
          hn[r] = x;
          htp[r] += qv*x;
        }
        hreg[g] = hn;
      }

      // reduce h_tilde partials over the 16 skill-lanes (lr)
      #pragma unroll
      for (int r = 0; r < 4; ++r) {
        float v = htp[r];
        v += __shfl_xor(v, 1, 64);
        v += __shfl_xor(v, 2, 64);
        v += __shfl_xor(v, 4, 64);
        v += __shfl_xor(v, 8, 64);
        htp[r] = v;
      }
      if (lr == 0) {
        #pragma unroll
        for (int r = 0; r < 4; ++r) htp_l[wn][jb + lg4*4 + r] = htp[r];
      }
      __syncthreads(); // b3
    }
  }
}

extern "C" void kernel_launch(void* const* d_in, const int* in_sizes, int n_in,
                              void* d_out, int out_size, void* d_ws, size_t ws_size,
                              hipStream_t stream) {
  const float* answer   = (const float*)d_in[0];
  const float* q_matrix = (const float*)d_in[1];
  const float* h0       = (const float*)d_in[2];
  const float* E_emb    = (const float*)d_in[3];
  const float* AT_emb   = (const float*)d_in[4];
  const float* IT_emb   = (const float*)d_in[5];
  const float* W_le     = (const float*)d_in[6];
  const float* b_le     = (const float*)d_in[7];
  const float* W_l      = (const float*)d_in[8];
  const float* b_l      = (const float*)d_in[9];
  const float* W_g      = (const float*)d_in[10];
  const float* b_g      = (const float*)d_in[11];
  const float* W_f      = (const float*)d_in[12];
  const float* b_f      = (const float*)d_in[13];
  const float* W_p      = (const float*)d_in[14];
  const float* b_p      = (const float*)d_in[15];
  const int* ex_id      = (const int*)d_in[16];
  const int* at_id      = (const int*)d_in[19];
  const int* it_sec     = (const int*)d_in[20];

  float* ws = (float*)d_ws;
  float* pred = (float*)d_out;

  k_learning<<<dim3(256), dim3(512), 0, stream>>>(E_emb, AT_emb, W_le, b_le, answer,
                                                  ex_id, at_id, ws + LEARN_OFF);
  k_pre<<<dim3(256), dim3(512), 0, stream>>>(IT_emb, E_emb, W_l, b_l, W_g, b_g,
                                             W_f, b_f, W_p, b_p, ex_id, it_sec,
                                             ws + LEARN_OFF, ws);
  k_scan<<<dim3(64), dim3(1024), 0, stream>>>(q_matrix, h0, W_l, W_g, W_f, W_p,
                                              ex_id, ws, pred);
}

// Round 9
// 1153.300 us; speedup vs baseline: 1.8024x; 1.7734x over previous
//
#include <hip/hip_runtime.h>
#include <hip/hip_bf16.h>
#include <stdint.h>

#define B_ 64
#define S_ 50
#define NSK 512
#define HROWS 256
#define DK 128

// ws layout (float offsets)
#define LEARN_OFF 0u
#define PREL_OFF  409600u
#define PREG_OFF  819200u
#define PREF_OFF  1228800u
#define PREP_OFF  1638400u
#define XCH_OFF   2048000u          // 64 pairs x 2 parity x 2 half x 128 = 32768 floats
#define FLAG_OFF  2080768u          // 128 ints

typedef float  f32x4  __attribute__((ext_vector_type(4)));
typedef short  s16x8  __attribute__((ext_vector_type(8)));
typedef __bf16 bf16x8 __attribute__((ext_vector_type(8)));

static __device__ __forceinline__ bf16x8 as_bf(s16x8 v){ return __builtin_bit_cast(bf16x8, v); }

static __device__ __forceinline__ unsigned short f2bf(float x){
  unsigned int u = __builtin_bit_cast(unsigned int, x);
  u += 0x7FFFu + ((u>>16)&1u);
  return (unsigned short)(u>>16);
}
static __device__ __forceinline__ float sigm(float x){ return 1.f/(1.f + __expf(-x)); }

// -------------------- K1: learning[b,t,j] --------------------
__global__ __launch_bounds__(512) void k_learning(
    const float* __restrict__ E_emb, const float* __restrict__ AT_emb,
    const float* __restrict__ W_le, const float* __restrict__ b_le,
    const float* __restrict__ answer, const int* __restrict__ ex_id,
    const int* __restrict__ at_id, float* __restrict__ learn_ws)
{
  int b = blockIdx.x >> 2, jg = blockIdx.x & 3;
  int tid = threadIdx.x; int w = tid >> 6; int l = tid & 63;
  __shared__ float exv[S_][128];
  __shared__ float atv[S_][128];
  __shared__ float ansv[S_];
  for (int idx = tid; idx < S_*128; idx += 512) {
    int t = idx >> 7, d = idx & 127;
    exv[t][d] = E_emb[(size_t)ex_id[b*S_+t]*128 + d];
    atv[t][d] = AT_emb[(size_t)at_id[b*S_+t]*128 + d];
  }
  if (tid < S_) ansv[tid] = answer[b*S_+tid];
  __syncthreads();
  for (int jj = 0; jj < 4; ++jj) {
    int jrow = jg*32 + w + 8*jj;
    float wv[5];
    int base = l*5;
    #pragma unroll
    for (int q = 0; q < 5; ++q) { int i = base+q; wv[q] = (i < 306) ? W_le[jrow*306 + i] : 0.f; }
    float bj = b_le[jrow];
    for (int t = 0; t < S_; ++t) {
      float pacc = 0.f;
      #pragma unroll
      for (int q = 0; q < 5; ++q) {
        int i = base+q;
        float v = 0.f;
        if (i < 128) v = exv[t][i];
        else if (i < 256) v = atv[t][i-128];
        else if (i < 306) v = ansv[t];
        pacc += wv[q]*v;
      }
      #pragma unroll
      for (int m = 1; m < 64; m <<= 1) pacc += __shfl_xor(pacc, m, 64);
      if (l == 0) learn_ws[(size_t)(b*S_+t)*DK + jrow] = pacc + bj;
    }
  }
}

// -------------------- K2: pre_l/pre_g/pre_f/pre_p --------------------
__global__ __launch_bounds__(512) void k_pre(
    const float* __restrict__ IT_emb, const float* __restrict__ E_emb,
    const float* __restrict__ W_l, const float* __restrict__ b_l,
    const float* __restrict__ W_g, const float* __restrict__ b_g,
    const float* __restrict__ W_f, const float* __restrict__ b_f,
    const float* __restrict__ W_p, const float* __restrict__ b_p,
    const int* __restrict__ ex_id, const int* __restrict__ it_sec,
    const float* __restrict__ learn_ws, float* __restrict__ ws)
{
  int b = blockIdx.x >> 2, jg = blockIdx.x & 3;
  int tid = threadIdx.x; int w = tid >> 6; int l = tid & 63;
  __shared__ float itv[S_][128];
  __shared__ float llds[S_][128];
  __shared__ float exv[S_][128];
  for (int idx = tid; idx < S_*128; idx += 512) {
    int t = idx >> 7, d = idx & 127;
    int itm = it_sec[b*S_+t] / 60; if (itm > 1439) itm = 1439; if (itm < 0) itm = 0;
    itv[t][d]  = IT_emb[(size_t)itm*128 + d];
    llds[t][d] = learn_ws[(size_t)(b*S_+t)*DK + d];
    exv[t][d]  = E_emb[(size_t)ex_id[b*S_+t]*128 + d];
  }
  __syncthreads();
  for (int jj = 0; jj < 4; ++jj) {
    int jrow = jg*32 + w + 8*jj;
    float wl[6], wg[6];
    int base6 = l*6;
    #pragma unroll
    for (int q = 0; q < 6; ++q) { wl[q] = W_l[jrow*512 + base6+q]; wg[q] = W_g[jrow*512 + base6+q]; }
    float wfv[2], wpv[2];
    int base2 = l*2;
    #pragma unroll
    for (int q = 0; q < 2; ++q) { wfv[q] = W_f[jrow*384 + 256 + base2+q]; wpv[q] = W_p[jrow*256 + base2+q]; }
    float bl = b_l[jrow], bg = b_g[jrow], bfs = b_f[jrow], bp = b_p[jrow];
    for (int t = 0; t < S_; ++t) {
      float pl = 0.f, pg = 0.f, pf = 0.f, pp = 0.f;
      #pragma unroll
      for (int q = 0; q < 6; ++q) {
        int i = base6+q;
        float v;
        if (i < 128) v = (t > 0) ? llds[t-1][i] : 0.f;
        else if (i < 256) v = itv[t][i-128];
        else v = llds[t][i-256];
        pl += wl[q]*v; pg += wg[q]*v;
      }
      #pragma unroll
      for (int q = 0; q < 2; ++q) {
        pf += wfv[q]*itv[t][base2+q];
        pp += wpv[q]*exv[t][base2+q];
      }
      #pragma unroll
      for (int m = 1; m < 64; m <<= 1) {
        pl += __shfl_xor(pl, m, 64);
        pg += __shfl_xor(pg, m, 64);
        pf += __shfl_xor(pf, m, 64);
        pp += __shfl_xor(pp, m, 64);
      }
      if (l == 0) {
        size_t o = (size_t)(b*S_+t)*DK + jrow;
        ws[PREL_OFF + o] = pl + bl;
        ws[PREG_OFF + o] = pg + bg;
        ws[PREF_OFF + o] = pf + bfs;
        ws[PREP_OFF + o] = pp + bp;
      }
    }
  }
}

// -------------------- K3: scan, 128 blocks (batch x skill-half), 512 thr --------------------
// block: b = bid>>1, half = bid&1, owns rows [half*256, half*256+256).
// wave w = j-sixteenth (16 dims). thread: hreg[16] f32x4 = 64 VGPRs of fp32 h.
__global__ __launch_bounds__(512) void k_scan(
    const float* __restrict__ q_matrix, const float* __restrict__ h0,
    const float* __restrict__ W_l, const float* __restrict__ W_g,
    const float* __restrict__ W_f, const float* __restrict__ W_p,
    const int* __restrict__ ex_id, float* __restrict__ ws,
    float* __restrict__ pred)
{
  int bid  = blockIdx.x;
  int b    = bid >> 1;
  int half = bid & 1;
  int tid = threadIdx.x;
  int w  = tid >> 6;          // wave 0..7 = j-sixteenth
  int l  = tid & 63;
  int lr  = l & 15;
  int lg4 = l >> 4;
  int jb  = w*16;
  int swz = (lr & 7) << 4;

  __shared__ __align__(16) unsigned short h_sh[HROWS*DK];  // 64KB bf16
  __shared__ float qbuf[2][HROWS];
  __shared__ float LG_l[DK];
  __shared__ float cf_l[DK];
  __shared__ float htp_l[DK];     // own-half h_tilde partial
  __shared__ float hts_l[DK];     // full h_tilde (own + partner)
  __shared__ float hinit[4][DK];
  __shared__ float ysum_l[8];

  float* xch = ws + XCH_OFF + (size_t)b*512;          // [parity][half][128]
  int*   flg = (int*)(ws + FLAG_OFF);
  int* flg_own = flg + b*2 + half;
  int* flg_par = flg + b*2 + (1-half);

  // ---- W_f1 fragments for this wave's j-tile: 16 VGPRs ----
  s16x8 wfr[4];
  #pragma unroll
  for (int k = 0; k < 4; ++k) {
    const float* src = W_f + (jb + lr)*384 + k*32 + lg4*8;
    s16x8 f;
    #pragma unroll
    for (int q = 0; q < 8; ++q) f[q] = (short)f2bf(src[q]);
    wfr[k] = f;
  }

  // ---- h master in registers: 16 rows x 4 dims = 64 VGPRs ----
  f32x4 hreg[16];
  #pragma unroll
  for (int g = 0; g < 16; ++g) {
    int row = half*HROWS + g*16 + lr;
    hreg[g] = *(const f32x4*)(h0 + (size_t)row*DK + jb + lg4*4);
  }

  if (tid < HROWS) qbuf[0][tid] = q_matrix[(size_t)ex_id[b*S_]*NSK + half*HROWS + tid];
  if (tid == 0 && half == 0) pred[b*S_] = 0.f;
  __syncthreads();
  // ---- h_tilde0 partial over own 256 rows ----
  {
    int d = tid & 127, gg = tid >> 7;  // gg 0..3, 64 rows each
    float acc = 0.f;
    for (int n = gg*64; n < gg*64 + 64; ++n)
      acc += qbuf[0][n] * h0[(size_t)(half*HROWS + n)*DK + d];
    hinit[gg][d] = acc;
  }
  __syncthreads();
  if (tid < DK) {
    float s = hinit[0][tid] + hinit[1][tid] + hinit[2][tid] + hinit[3][tid];
    htp_l[tid] = s;
    __hip_atomic_store(&xch[0*256 + half*128 + tid], s,
                       __ATOMIC_RELAXED, __HIP_MEMORY_SCOPE_AGENT);
  }
  __syncthreads();
  if (tid == 0)
    __hip_atomic_store(flg_own, 1, __ATOMIC_RELEASE, __HIP_MEMORY_SCOPE_AGENT);

  const float* pre_l = ws + PREL_OFF + (size_t)b*S_*DK;
  const float* pre_g = ws + PREG_OFF + (size_t)b*S_*DK;
  const float* pre_f = ws + PREF_OFF + (size_t)b*S_*DK;
  const float* pre_p = ws + PREP_OFF + (size_t)b*S_*DK;

  int jrow = tid >> 2, p = tid & 3;

  for (int tau = 0; tau < S_; ++tau) {
    // ---- wait for partner's h_tilde partial (exchange #tau), combine ----
    if (tid == 0) {
      while (__hip_atomic_load(flg_par, __ATOMIC_ACQUIRE, __HIP_MEMORY_SCOPE_AGENT) < tau + 1)
        __builtin_amdgcn_s_sleep(8);
    }
    __syncthreads(); // b0
    if (tid < DK)
      hts_l[tid] = htp_l[tid] +
        __hip_atomic_load(&xch[(tau&1)*256 + (1-half)*128 + tid],
                          __ATOMIC_RELAXED, __HIP_MEMORY_SCOPE_AGENT);
    __syncthreads(); // b0b

    // ================= G1: LG + y(tau) + q staging =================
    {
      float accL = 0.f, accG = 0.f, accY = 0.f;
      const float* wl4 = W_l + jrow*512 + 384;
      const float* wg4 = W_g + jrow*512 + 384;
      const float* wp2 = W_p + jrow*256 + 128;
      #pragma unroll
      for (int c0 = 0; c0 < 32; c0 += 4) {
        int c = p*32 + c0;
        f32x4 hv = *(const f32x4*)&hts_l[c];
        f32x4 a  = *(const f32x4*)(wl4 + c);
        f32x4 g4 = *(const f32x4*)(wg4 + c);
        f32x4 y4 = *(const f32x4*)(wp2 + c);
        accL += a[0]*hv[0] + a[1]*hv[1] + a[2]*hv[2] + a[3]*hv[3];
        accG += g4[0]*hv[0] + g4[1]*hv[1] + g4[2]*hv[2] + g4[3]*hv[3];
        accY += y4[0]*hv[0] + y4[1]*hv[1] + y4[2]*hv[2] + y4[3]*hv[3];
      }
      accL += __shfl_xor(accL, 1, 64); accL += __shfl_xor(accL, 2, 64);
      accG += __shfl_xor(accG, 1, 64); accG += __shfl_xor(accG, 2, 64);
      accY += __shfl_xor(accY, 1, 64); accY += __shfl_xor(accY, 2, 64);
      float xl = pre_l[tau*DK + jrow] + accL;
      float xg = pre_g[tau*DK + jrow] + accG;
      float LG = sigm(xg) * (tanhf(xl) + 1.f) * 0.5f;
      if (p == 0) LG_l[jrow] = LG;
      float sg = 0.f;
      if (tau > 0 && p == 0) sg = sigm(pre_p[tau*DK + jrow] + accY);
      #pragma unroll
      for (int m = 4; m < 64; m <<= 1) sg += __shfl_xor(sg, m, 64);
      if (l == 0) ysum_l[w] = sg;
      if (tau < S_-1 && tid < HROWS)
        qbuf[(tau+1)&1][tid] = q_matrix[(size_t)ex_id[b*S_+tau+1]*NSK + half*HROWS + tid];
    }
    __syncthreads(); // b1
    if (tid == 0 && tau > 0 && half == 0) {
      float s = 0.f;
      #pragma unroll
      for (int i = 0; i < 8; ++i) s += ysum_l[i];
      pred[b*S_ + tau] = s * (1.f/128.f);
    }

    if (tau < S_-1) {
      // ============ G2: cf = pre_f + W_f2 @ LG ; pack h_sh from hreg ============
      {
        float accF = 0.f;
        const float* wf2 = W_f + jrow*384 + 128;
        #pragma unroll
        for (int c0 = 0; c0 < 32; c0 += 4) {
          int c = p*32 + c0;
          f32x4 a   = *(const f32x4*)(wf2 + c);
          f32x4 lgv = *(const f32x4*)&LG_l[c];
          accF += a[0]*lgv[0] + a[1]*lgv[1] + a[2]*lgv[2] + a[3]*lgv[3];
        }
        accF += __shfl_xor(accF, 1, 64); accF += __shfl_xor(accF, 2, 64);
        if (p == 0) cf_l[jrow] = pre_f[tau*DK + jrow] + accF;
      }
      // pack bf16 shadow of own-half h (8B writes)
      #pragma unroll
      for (int g = 0; g < 16; ++g) {
        int rl = g*16 + lr;
        int cb = jb*2 + lg4*8;
        f32x4 hv = hreg[g];
        unsigned long long pkv =
            (unsigned long long)f2bf(hv[0])
          | ((unsigned long long)f2bf(hv[1]) << 16)
          | ((unsigned long long)f2bf(hv[2]) << 32)
          | ((unsigned long long)f2bf(hv[3]) << 48);
        *(unsigned long long*)((char*)h_sh + (rl*256 + (cb ^ swz))) = pkv;
      }
      __syncthreads(); // b2

      // ============ M: MFMA (acc init = cf) + update + h_tilde accum ============
      const float* qc = qbuf[tau&1];
      const float* qn = qbuf[(tau+1)&1];
      f32x4 cfv = *(const f32x4*)&cf_l[jb + lg4*4];
      f32x4 lgv = *(const f32x4*)&LG_l[jb + lg4*4];
      f32x4 htp = (f32x4){0.f,0.f,0.f,0.f};

      #pragma unroll
      for (int g = 0; g < 16; ++g) {
        int rl = g*16 + lr;
        const char* rowp = (const char*)h_sh + rl*256;
        f32x4 acc = cfv;
        #pragma unroll
        for (int k = 0; k < 4; ++k) {
          s16x8 bfr = *(const s16x8*)(rowp + ((k*64 + lg4*16) ^ swz));
          acc = __builtin_amdgcn_mfma_f32_16x16x32_bf16(as_bf(wfr[k]), as_bf(bfr), acc, 0, 0, 0);
        }
        float qt = qc[rl];
        float qv = qn[rl];
        f32x4 hv = hreg[g];
        f32x4 hn;
        #pragma unroll
        for (int r = 0; r < 4; ++r) {
          float x = qt*lgv[r] + sigm(acc[r])*hv[r];
          hn[r] = x;
          htp[r] += qv*x;
        }
        hreg[g] = hn;
      }

      #pragma unroll
      for (int r = 0; r < 4; ++r) {
        float v = htp[r];
        v += __shfl_xor(v, 1, 64);
        v += __shfl_xor(v, 2, 64);
        v += __shfl_xor(v, 4, 64);
        v += __shfl_xor(v, 8, 64);
        htp[r] = v;
      }
      if (lr == 0) {
        #pragma unroll
        for (int r = 0; r < 4; ++r) htp_l[jb + lg4*4 + r] = htp[r];
      }
      __syncthreads(); // b3

      // ---- publish own partial (exchange #tau+1) ----
      if (tid < DK)
        __hip_atomic_store(&xch[((tau+1)&1)*256 + half*128 + tid], htp_l[tid],
                           __ATOMIC_RELAXED, __HIP_MEMORY_SCOPE_AGENT);
      __syncthreads(); // b4
      if (tid == 0)
        __hip_atomic_store(flg_own, tau + 2, __ATOMIC_RELEASE, __HIP_MEMORY_SCOPE_AGENT);
    }
  }
}

extern "C" void kernel_launch(void* const* d_in, const int* in_sizes, int n_in,
                              void* d_out, int out_size, void* d_ws, size_t ws_size,
                              hipStream_t stream) {
  const float* answer   = (const float*)d_in[0];
  const float* q_matrix = (const float*)d_in[1];
  const float* h0       = (const float*)d_in[2];
  const float* E_emb    = (const float*)d_in[3];
  const float* AT_emb   = (const float*)d_in[4];
  const float* IT_emb   = (const float*)d_in[5];
  const float* W_le     = (const float*)d_in[6];
  const float* b_le     = (const float*)d_in[7];
  const float* W_l      = (const float*)d_in[8];
  const float* b_l      = (const float*)d_in[9];
  const float* W_g      = (const float*)d_in[10];
  const float* b_g      = (const float*)d_in[11];
  const float* W_f      = (const float*)d_in[12];
  const float* b_f      = (const float*)d_in[13];
  const float* W_p      = (const float*)d_in[14];
  const float* b_p      = (const float*)d_in[15];
  const int* ex_id      = (const int*)d_in[16];
  const int* at_id      = (const int*)d_in[19];
  const int* it_sec     = (const int*)d_in[20];

  float* ws = (float*)d_ws;
  float* pred = (float*)d_out;

  k_learning<<<dim3(256), dim3(512), 0, stream>>>(E_emb, AT_emb, W_le, b_le, answer,
                                                  ex_id, at_id, ws + LEARN_OFF);
  k_pre<<<dim3(256), dim3(512), 0, stream>>>(IT_emb, E_emb, W_l, b_l, W_g, b_g,
                                             W_f, b_f, W_p, b_p, ex_id, it_sec,
                                             ws + LEARN_OFF, ws);
  // zero the pair-sync flags (captured as part of the graph)
  hipMemsetAsync((char*)d_ws + (size_t)FLAG_OFF*4, 0, 128*sizeof(int), stream);

  void* args[] = { (void*)&q_matrix, (void*)&h0, (void*)&W_l, (void*)&W_g,
                   (void*)&W_f, (void*)&W_p, (void*)&ex_id, (void*)&ws, (void*)&pred };
  hipLaunchCooperativeKernel((const void*)k_scan, dim3(128), dim3(512), args, 0, stream);
}

// Round 10
// 983.616 us; speedup vs baseline: 2.1134x; 1.1725x over previous
//
#include <hip/hip_runtime.h>
#include <hip/hip_bf16.h>
#include <stdint.h>

#define B_ 64
#define S_ 50
#define NSK 512
#define QROWS 128
#define DK 128

// ws layout (float offsets)
#define LEARN_OFF 0u
#define PREL_OFF  409600u
#define PREG_OFF  819200u
#define PREF_OFF  1228800u
#define PREP_OFF  1638400u
#define XCH_OFF   2048000u          // 64 batches x 2 parity x 4 quarter x 2 wn2 x 128 = 131072 floats
#define FLAG_OFF  2179072u          // 256 ints

typedef float  f32x4  __attribute__((ext_vector_type(4)));
typedef short  s16x8  __attribute__((ext_vector_type(8)));
typedef __bf16 bf16x8 __attribute__((ext_vector_type(8)));

static __device__ __forceinline__ bf16x8 as_bf(s16x8 v){ return __builtin_bit_cast(bf16x8, v); }

static __device__ __forceinline__ unsigned short f2bf(float x){
  unsigned int u = __builtin_bit_cast(unsigned int, x);
  u += 0x7FFFu + ((u>>16)&1u);
  return (unsigned short)(u>>16);
}
static __device__ __forceinline__ float sigm(float x){ return 1.f/(1.f + __expf(-x)); }

// -------------------- K1: learning[b,t,j] --------------------
__global__ __launch_bounds__(512) void k_learning(
    const float* __restrict__ E_emb, const float* __restrict__ AT_emb,
    const float* __restrict__ W_le, const float* __restrict__ b_le,
    const float* __restrict__ answer, const int* __restrict__ ex_id,
    const int* __restrict__ at_id, float* __restrict__ learn_ws)
{
  int b = blockIdx.x >> 2, jg = blockIdx.x & 3;
  int tid = threadIdx.x; int w = tid >> 6; int l = tid & 63;
  __shared__ float exv[S_][128];
  __shared__ float atv[S_][128];
  __shared__ float ansv[S_];
  for (int idx = tid; idx < S_*128; idx += 512) {
    int t = idx >> 7, d = idx & 127;
    exv[t][d] = E_emb[(size_t)ex_id[b*S_+t]*128 + d];
    atv[t][d] = AT_emb[(size_t)at_id[b*S_+t]*128 + d];
  }
  if (tid < S_) ansv[tid] = answer[b*S_+tid];
  __syncthreads();
  for (int jj = 0; jj < 4; ++jj) {
    int jrow = jg*32 + w + 8*jj;
    float wv[5];
    int base = l*5;
    #pragma unroll
    for (int q = 0; q < 5; ++q) { int i = base+q; wv[q] = (i < 306) ? W_le[jrow*306 + i] : 0.f; }
    float bj = b_le[jrow];
    for (int t = 0; t < S_; ++t) {
      float pacc = 0.f;
      #pragma unroll
      for (int q = 0; q < 5; ++q) {
        int i = base+q;
        float v = 0.f;
        if (i < 128) v = exv[t][i];
        else if (i < 256) v = atv[t][i-128];
        else if (i < 306) v = ansv[t];
        pacc += wv[q]*v;
      }
      #pragma unroll
      for (int m = 1; m < 64; m <<= 1) pacc += __shfl_xor(pacc, m, 64);
      if (l == 0) learn_ws[(size_t)(b*S_+t)*DK + jrow] = pacc + bj;
    }
  }
}

// -------------------- K2: pre_l/pre_g/pre_f/pre_p --------------------
__global__ __launch_bounds__(512) void k_pre(
    const float* __restrict__ IT_emb, const float* __restrict__ E_emb,
    const float* __restrict__ W_l, const float* __restrict__ b_l,
    const float* __restrict__ W_g, const float* __restrict__ b_g,
    const float* __restrict__ W_f, const float* __restrict__ b_f,
    const float* __restrict__ W_p, const float* __restrict__ b_p,
    const int* __restrict__ ex_id, const int* __restrict__ it_sec,
    const float* __restrict__ learn_ws, float* __restrict__ ws)
{
  int b = blockIdx.x >> 2, jg = blockIdx.x & 3;
  int tid = threadIdx.x; int w = tid >> 6; int l = tid & 63;
  __shared__ float itv[S_][128];
  __shared__ float llds[S_][128];
  __shared__ float exv[S_][128];
  for (int idx = tid; idx < S_*128; idx += 512) {
    int t = idx >> 7, d = idx & 127;
    int itm = it_sec[b*S_+t] / 60; if (itm > 1439) itm = 1439; if (itm < 0) itm = 0;
    itv[t][d]  = IT_emb[(size_t)itm*128 + d];
    llds[t][d] = learn_ws[(size_t)(b*S_+t)*DK + d];
    exv[t][d]  = E_emb[(size_t)ex_id[b*S_+t]*128 + d];
  }
  __syncthreads();
  for (int jj = 0; jj < 4; ++jj) {
    int jrow = jg*32 + w + 8*jj;
    float wl[6], wg[6];
    int base6 = l*6;
    #pragma unroll
    for (int q = 0; q < 6; ++q) { wl[q] = W_l[jrow*512 + base6+q]; wg[q] = W_g[jrow*512 + base6+q]; }
    float wfv[2], wpv[2];
    int base2 = l*2;
    #pragma unroll
    for (int q = 0; q < 2; ++q) { wfv[q] = W_f[jrow*384 + 256 + base2+q]; wpv[q] = W_p[jrow*256 + base2+q]; }
    float bl = b_l[jrow], bg = b_g[jrow], bfs = b_f[jrow], bp = b_p[jrow];
    for (int t = 0; t < S_; ++t) {
      float pl = 0.f, pg = 0.f, pf = 0.f, pp = 0.f;
      #pragma unroll
      for (int q = 0; q < 6; ++q) {
        int i = base6+q;
        float v;
        if (i < 128) v = (t > 0) ? llds[t-1][i] : 0.f;
        else if (i < 256) v = itv[t][i-128];
        else v = llds[t][i-256];
        pl += wl[q]*v; pg += wg[q]*v;
      }
      #pragma unroll
      for (int q = 0; q < 2; ++q) {
        pf += wfv[q]*itv[t][base2+q];
        pp += wpv[q]*exv[t][base2+q];
      }
      #pragma unroll
      for (int m = 1; m < 64; m <<= 1) {
        pl += __shfl_xor(pl, m, 64);
        pg += __shfl_xor(pg, m, 64);
        pf += __shfl_xor(pf, m, 64);
        pp += __shfl_xor(pp, m, 64);
      }
      if (l == 0) {
        size_t o = (size_t)(b*S_+t)*DK + jrow;
        ws[PREL_OFF + o] = pl + bl;
        ws[PREG_OFF + o] = pg + bg;
        ws[PREF_OFF + o] = pf + bfs;
        ws[PREP_OFF + o] = pp + bp;
      }
    }
  }
}

// -------------------- K3: scan, 256 blocks (batch x skill-quarter), 512 thr --------------------
// quarter q owns global rows [q*128, q*128+128). wave (wn2 = w>>2, wj4 = w&3):
// local rows [wn2*64,+64), j-dims [wj4*32,+32). thread: hreg[4][2] f32x4 (32 regs).
__global__ __launch_bounds__(512) void k_scan(
    const float* __restrict__ q_matrix, const float* __restrict__ h0,
    const float* __restrict__ W_l, const float* __restrict__ W_g,
    const float* __restrict__ W_f, const float* __restrict__ W_p,
    const int* __restrict__ ex_id, float* __restrict__ ws,
    float* __restrict__ pred)
{
  int bid = blockIdx.x;
  int xcd = bid & 7, rr = bid >> 3;
  int q = rr & 3;
  int b = xcd + 8*(rr >> 2);
  int tid = threadIdx.x;
  int w  = tid >> 6;
  int l  = tid & 63;
  int wn2 = w >> 2;           // local row half (64 rows)
  int wj4 = w & 3;            // j-quarter (32 dims)
  int lr  = l & 15;
  int lg4 = l >> 4;
  int swz = lr << 4;          // 4-bit row XOR swizzle

  __shared__ __align__(16) unsigned short h_sh[QROWS*DK];  // 32KB bf16, swizzled
  __shared__ float qbuf[2][QROWS];
  __shared__ float LG_l[DK];
  __shared__ float cf_l[DK];
  __shared__ float htp_l2[2][DK];   // per-wn2 own h_tilde partials
  __shared__ float hts_l[DK];       // combined h_tilde
  __shared__ float hinit[4][DK];
  __shared__ float ysum_l[8];

  float* xch = ws + XCH_OFF + (size_t)b*2048;   // [parity][quarter][wn2][128]
  int*   flg = (int*)(ws + FLAG_OFF) + b*4;

  // ---- W_f1 fragments: 2 jt x 4 k = 32 VGPRs ----
  s16x8 wfr[2][4];
  #pragma unroll
  for (int jt = 0; jt < 2; ++jt) {
    #pragma unroll
    for (int k = 0; k < 4; ++k) {
      int jrow_ = wj4*32 + jt*16 + lr;
      const float* src = W_f + jrow_*384 + k*32 + lg4*8;
      s16x8 f;
      #pragma unroll
      for (int qq = 0; qq < 8; ++qq) f[qq] = (short)f2bf(src[qq]);
      wfr[jt][k] = f;
    }
  }

  // ---- h master: 4 row-tiles x 2 j-tiles = 32 VGPRs ----
  f32x4 hreg[4][2];
  #pragma unroll
  for (int g = 0; g < 4; ++g) {
    int row = q*QROWS + wn2*64 + g*16 + lr;
    #pragma unroll
    for (int jt = 0; jt < 2; ++jt) {
      int db = wj4*32 + jt*16 + lg4*4;
      hreg[g][jt] = *(const f32x4*)(h0 + (size_t)row*DK + db);
    }
  }

  if (tid < QROWS) qbuf[0][tid] = q_matrix[(size_t)ex_id[b*S_]*NSK + q*QROWS + tid];
  if (tid == 0 && q == 0) pred[b*S_] = 0.f;
  __syncthreads();
  // ---- h_tilde0 partial over own 128 rows ----
  {
    int d = tid & 127, gg = tid >> 7;   // gg 0..3, 32 rows each
    float acc = 0.f;
    for (int n = gg*32; n < gg*32 + 32; ++n)
      acc += qbuf[0][n] * h0[(size_t)(q*QROWS + n)*DK + d];
    hinit[gg][d] = acc;
  }
  __syncthreads();
  if (tid < DK) {
    float s = hinit[0][tid] + hinit[1][tid] + hinit[2][tid] + hinit[3][tid];
    htp_l2[0][tid] = s;
    htp_l2[1][tid] = 0.f;
    __hip_atomic_store(&xch[q*256 + tid], s, __ATOMIC_RELAXED, __HIP_MEMORY_SCOPE_AGENT);
    __hip_atomic_store(&xch[q*256 + 128 + tid], 0.f, __ATOMIC_RELAXED, __HIP_MEMORY_SCOPE_AGENT);
  }
  __syncthreads();
  if (tid == 0)
    __hip_atomic_store(&flg[q], 1, __ATOMIC_RELEASE, __HIP_MEMORY_SCOPE_AGENT);

  const float* pre_l = ws + PREL_OFF + (size_t)b*S_*DK;
  const float* pre_g = ws + PREG_OFF + (size_t)b*S_*DK;
  const float* pre_f = ws + PREF_OFF + (size_t)b*S_*DK;
  const float* pre_p = ws + PREP_OFF + (size_t)b*S_*DK;

  int jrow = tid >> 2, p = tid & 3;

  for (int tau = 0; tau < S_; ++tau) {
    // ---- PACK h_sh from hreg (no partner dependency -> hides handshake) ----
    if (tau < S_-1) {
      #pragma unroll
      for (int g = 0; g < 4; ++g) {
        int rl = wn2*64 + g*16 + lr;
        #pragma unroll
        for (int jt = 0; jt < 2; ++jt) {
          int cb = wj4*64 + jt*32 + lg4*8;
          f32x4 hv = hreg[g][jt];
          unsigned long long pkv =
              (unsigned long long)f2bf(hv[0])
            | ((unsigned long long)f2bf(hv[1]) << 16)
            | ((unsigned long long)f2bf(hv[2]) << 32)
            | ((unsigned long long)f2bf(hv[3]) << 48);
          *(unsigned long long*)((char*)h_sh + (rl*256 + (cb ^ swz))) = pkv;
        }
      }
    }
    // ---- wait for the 3 sibling quarters (parallel polls) ----
    if (tid < 3) {
      int qq = (tid >= q) ? tid + 1 : tid;
      while (__hip_atomic_load(&flg[qq], __ATOMIC_ACQUIRE, __HIP_MEMORY_SCOPE_AGENT) < tau + 1)
        __builtin_amdgcn_s_sleep(2);
    }
    __syncthreads(); // b0
    if (tid < DK) {
      float s = htp_l2[0][tid] + htp_l2[1][tid];
      #pragma unroll
      for (int qq = 0; qq < 4; ++qq) {
        if (qq == q) continue;
        s += __hip_atomic_load(&xch[(tau&1)*1024 + qq*256 + tid], __ATOMIC_RELAXED, __HIP_MEMORY_SCOPE_AGENT);
        s += __hip_atomic_load(&xch[(tau&1)*1024 + qq*256 + 128 + tid], __ATOMIC_RELAXED, __HIP_MEMORY_SCOPE_AGENT);
      }
      hts_l[tid] = s;
    }
    __syncthreads(); // b0b

    // ================= G1: LG + y(tau) + q staging =================
    {
      float accL = 0.f, accG = 0.f, accY = 0.f;
      const float* wl4 = W_l + jrow*512 + 384;
      const float* wg4 = W_g + jrow*512 + 384;
      const float* wp2 = W_p + jrow*256 + 128;
      #pragma unroll
      for (int c0 = 0; c0 < 32; c0 += 4) {
        int c = p*32 + c0;
        f32x4 hv = *(const f32x4*)&hts_l[c];
        f32x4 a  = *(const f32x4*)(wl4 + c);
        f32x4 g4 = *(const f32x4*)(wg4 + c);
        f32x4 y4 = *(const f32x4*)(wp2 + c);
        accL += a[0]*hv[0] + a[1]*hv[1] + a[2]*hv[2] + a[3]*hv[3];
        accG += g4[0]*hv[0] + g4[1]*hv[1] + g4[2]*hv[2] + g4[3]*hv[3];
        accY += y4[0]*hv[0] + y4[1]*hv[1] + y4[2]*hv[2] + y4[3]*hv[3];
      }
      accL += __shfl_xor(accL, 1, 64); accL += __shfl_xor(accL, 2, 64);
      accG += __shfl_xor(accG, 1, 64); accG += __shfl_xor(accG, 2, 64);
      accY += __shfl_xor(accY, 1, 64); accY += __shfl_xor(accY, 2, 64);
      float xl = pre_l[tau*DK + jrow] + accL;
      float xg = pre_g[tau*DK + jrow] + accG;
      float LG = sigm(xg) * (tanhf(xl) + 1.f) * 0.5f;
      if (p == 0) LG_l[jrow] = LG;
      float sg = 0.f;
      if (tau > 0 && p == 0) sg = sigm(pre_p[tau*DK + jrow] + accY);
      #pragma unroll
      for (int m = 4; m < 64; m <<= 1) sg += __shfl_xor(sg, m, 64);
      if (l == 0) ysum_l[w] = sg;
      if (tau < S_-1 && tid < QROWS)
        qbuf[(tau+1)&1][tid] = q_matrix[(size_t)ex_id[b*S_+tau+1]*NSK + q*QROWS + tid];
    }
    __syncthreads(); // b1
    if (tid == 0 && tau > 0 && q == 0) {
      float s = 0.f;
      #pragma unroll
      for (int i = 0; i < 8; ++i) s += ysum_l[i];
      pred[b*S_ + tau] = s * (1.f/128.f);
    }

    if (tau < S_-1) {
      // ============ G2: cf = pre_f + W_f2 @ LG ============
      {
        float accF = 0.f;
        const float* wf2 = W_f + jrow*384 + 128;
        #pragma unroll
        for (int c0 = 0; c0 < 32; c0 += 4) {
          int c = p*32 + c0;
          f32x4 a   = *(const f32x4*)(wf2 + c);
          f32x4 lgv = *(const f32x4*)&LG_l[c];
          accF += a[0]*lgv[0] + a[1]*lgv[1] + a[2]*lgv[2] + a[3]*lgv[3];
        }
        accF += __shfl_xor(accF, 1, 64); accF += __shfl_xor(accF, 2, 64);
        if (p == 0) cf_l[jrow] = pre_f[tau*DK + jrow] + accF;
      }
      __syncthreads(); // b2

      // ============ M: MFMA (acc init = cf) + update + h_tilde accum ============
      const float* qc = qbuf[tau&1];
      const float* qn = qbuf[(tau+1)&1];
      int db0 = wj4*32 + lg4*4;
      f32x4 cf0 = *(const f32x4*)&cf_l[db0];
      f32x4 cf1 = *(const f32x4*)&cf_l[db0 + 16];
      f32x4 lg0 = *(const f32x4*)&LG_l[db0];
      f32x4 lg1 = *(const f32x4*)&LG_l[db0 + 16];
      f32x4 htp0 = (f32x4){0.f,0.f,0.f,0.f};
      f32x4 htp1 = (f32x4){0.f,0.f,0.f,0.f};

      #pragma unroll
      for (int g = 0; g < 4; ++g) {
        int rl = wn2*64 + g*16 + lr;
        const char* rowp = (const char*)h_sh + rl*256;
        f32x4 acc0 = cf0, acc1 = cf1;
        #pragma unroll
        for (int k = 0; k < 4; ++k) {
          s16x8 bfr = *(const s16x8*)(rowp + ((k*64 + lg4*16) ^ swz));
          acc0 = __builtin_amdgcn_mfma_f32_16x16x32_bf16(as_bf(wfr[0][k]), as_bf(bfr), acc0, 0, 0, 0);
          acc1 = __builtin_amdgcn_mfma_f32_16x16x32_bf16(as_bf(wfr[1][k]), as_bf(bfr), acc1, 0, 0, 0);
        }
        float qt = qc[rl];
        float qv = qn[rl];
        #pragma unroll
        for (int r = 0; r < 4; ++r) {
          float x0 = qt*lg0[r] + sigm(acc0[r])*hreg[g][0][r];
          float x1 = qt*lg1[r] + sigm(acc1[r])*hreg[g][1][r];
          hreg[g][0][r] = x0;
          hreg[g][1][r] = x1;
          htp0[r] += qv*x0;
          htp1[r] += qv*x1;
        }
      }

      // lane-reduce over the 16 skill-lanes, publish directly
      #pragma unroll
      for (int r = 0; r < 4; ++r) {
        float v0 = htp0[r], v1 = htp1[r];
        v0 += __shfl_xor(v0, 1, 64); v1 += __shfl_xor(v1, 1, 64);
        v0 += __shfl_xor(v0, 2, 64); v1 += __shfl_xor(v1, 2, 64);
        v0 += __shfl_xor(v0, 4, 64); v1 += __shfl_xor(v1, 4, 64);
        v0 += __shfl_xor(v0, 8, 64); v1 += __shfl_xor(v1, 8, 64);
        htp0[r] = v0; htp1[r] = v1;
      }
      if (lr == 0) {
        size_t xb = ((tau+1)&1)*1024 + q*256 + wn2*128;
        #pragma unroll
        for (int r = 0; r < 4; ++r) {
          int d0 = db0 + r, d1 = db0 + 16 + r;
          htp_l2[wn2][d0] = htp0[r];
          htp_l2[wn2][d1] = htp1[r];
          __hip_atomic_store(&xch[xb + d0], htp0[r], __ATOMIC_RELAXED, __HIP_MEMORY_SCOPE_AGENT);
          __hip_atomic_store(&xch[xb + d1], htp1[r], __ATOMIC_RELAXED, __HIP_MEMORY_SCOPE_AGENT);
        }
      }
      __syncthreads(); // b3 (drains stores)
      if (tid == 0)
        __hip_atomic_store(&flg[q], tau + 2, __ATOMIC_RELEASE, __HIP_MEMORY_SCOPE_AGENT);
    }
  }
}

extern "C" void kernel_launch(void* const* d_in, const int* in_sizes, int n_in,
                              void* d_out, int out_size, void* d_ws, size_t ws_size,
                              hipStream_t stream) {
  const float* answer   = (const float*)d_in[0];
  const float* q_matrix = (const float*)d_in[1];
  const float* h0       = (const float*)d_in[2];
  const float* E_emb    = (const float*)d_in[3];
  const float* AT_emb   = (const float*)d_in[4];
  const float* IT_emb   = (const float*)d_in[5];
  const float* W_le     = (const float*)d_in[6];
  const float* b_le     = (const float*)d_in[7];
  const float* W_l      = (const float*)d_in[8];
  const float* b_l      = (const float*)d_in[9];
  const float* W_g      = (const float*)d_in[10];
  const float* b_g      = (const float*)d_in[11];
  const float* W_f      = (const float*)d_in[12];
  const float* b_f      = (const float*)d_in[13];
  const float* W_p      = (const float*)d_in[14];
  const float* b_p      = (const float*)d_in[15];
  const int* ex_id      = (const int*)d_in[16];
  const int* at_id      = (const int*)d_in[19];
  const int* it_sec     = (const int*)d_in[20];

  float* ws = (float*)d_ws;
  float* pred = (float*)d_out;

  k_learning<<<dim3(256), dim3(512), 0, stream>>>(E_emb, AT_emb, W_le, b_le, answer,
                                                  ex_id, at_id, ws + LEARN_OFF);
  k_pre<<<dim3(256), dim3(512), 0, stream>>>(IT_emb, E_emb, W_l, b_l, W_g, b_g,
                                             W_f, b_f, W_p, b_p, ex_id, it_sec,
                                             ws + LEARN_OFF, ws);
  // zero the quarter-sync flags (captured in the graph)
  hipMemsetAsync((char*)d_ws + (size_t)FLAG_OFF*4, 0, 256*sizeof(int), stream);

  void* args[] = { (void*)&q_matrix, (void*)&h0, (void*)&W_l, (void*)&W_g,
                   (void*)&W_f, (void*)&W_p, (void*)&ex_id, (void*)&ws, (void*)&pred };
  hipLaunchCooperativeKernel((const void*)k_scan, dim3(256), dim3(512), args, 0, stream);
}